// Round 16
// baseline (40.438 us; speedup 1.0000x reference)
//
#include <hip/hip_runtime.h>

// Grouped conv1d over W + roll(+1) along H, bf16 MFMA 16x16x32. SINGLE dispatch.
// x: (128, 48, 28, 28) f32, channel = g*24+ci
// w: (24, 96, 7) f32, w[ci][o][k], shared across the 2 groups
// out: (128, 192, 28, 28) f32, channel = g*96+o
//
// R16 = R10 compute/epilogue + R7 in-block w->LDS bounce, one kernel:
// R10 (wfrag pre-dispatch + conv) = 28.2us where conv alone ~25us; the tiny
// serialized wfrag dispatch costs ~3us of wall. R7/R9 proved the bounce is
// cheap in-block. Order: issue x loads (MLP) -> w float4 -> wbf LDS ->
// barrier -> extract B (48 ds_read_u16) -> barrier -> xs write (aliases wbf)
// -> barrier -> R10 compute + aligned float4 quad stores.
//
// GEMM per tile: M=112 (4 output rows x 28 W), N=96, K=168 pad 192.
// k-permutation (A and B must match): q = ks*4+kgrp (0..23);
//   q<21: k=q/3, ci=(q%3)*8+j ; q>=21: zero (B side).
// Block owns OUTPUT rows 4ht..4ht+3; src rows (4ht+hl-1) mod 28 absorb roll.

typedef __attribute__((ext_vector_type(8))) short short8;
typedef __attribute__((ext_vector_type(4))) float float4v;

#define B_     128
#define H_     28
#define W_     28
#define CIN_   24
#define COUT_  96
#define K_     7
#define KSTEPS 6
#define NT_    6
#define MT_    7
#define HW_    784

// packed 2x f32 -> bf16x2, one instruction
static __device__ __forceinline__ unsigned cvt_pk_bf16(float a, float b) {
    unsigned r;
    asm("v_cvt_pk_bf16_f32 %0, %1, %2" : "=v"(r) : "v"(a), "v"(b));
    return r;
}

__global__ __launch_bounds__(384, 4)
void conv_mfma_kernel(const float* __restrict__ x,
                      const float* __restrict__ w,
                      float* __restrict__ out) {
    const int bid = blockIdx.x;           // (b*2+g)*7 + ht
    const int ht  = bid % 7;
    const int bg  = bid / 7;
    const int g   = bg & 1;
    const int b   = bg >> 1;
    const int tid  = threadIdx.x;
    const int lane = tid & 63;
    const int nt   = tid >> 6;            // wave = N-tile, 0..5
    const int cgrp = lane & 15;
    const int kgrp = lane >> 4;

    // LDS: wbf[24][96][7] bf16 = 32256B; xs (6912B) aliases it afterwards.
    __shared__ __align__(16) short smem[16128];
    short* wbf = smem;
    short* xs  = smem;

    // ---- (1) issue x stage loads first: 1728 packed dwords, max MLP
    float v0r[5], v1r[5];
#pragma unroll
    for (int it = 0; it < 5; ++it) {
        const int idx = tid + it * 384;
        if (idx < 1728) {
            const int p  = idx % 36;
            const int r  = idx / 36;
            const int cp = r % 12;
            const int hl = r / 12;
            const int ws = p - 3;
            const int rsrc = (4 * ht + hl + 27) % 28;   // roll absorbed
            float a0 = 0.0f, a1 = 0.0f;
            if (ws >= 0 && ws < W_) {
                const size_t base =
                    ((size_t)(b * 48 + g * CIN_ + cp * 2) * H_ + rsrc) * W_ + ws;
                a0 = x[base];
                a1 = x[base + (size_t)HW_];
            }
            v0r[it] = a0; v1r[it] = a1;
        }
    }

    // ---- (2) w -> bf16 LDS bounce (coalesced float4, L2-hot; same linear order)
    for (int i = tid; i < 4032; i += 384) {
        const float4 v = ((const float4*)w)[i];
        ((uint2*)wbf)[i] = make_uint2(cvt_pk_bf16(v.x, v.y), cvt_pk_bf16(v.z, v.w));
    }
    __syncthreads();

    // ---- (3) B fragments -> 24 VGPR (48 ds_read_u16/lane, once per block)
    const int c_out = nt * 16 + cgrp;     // 0..95 within group
    short8 br[KSTEPS];
#pragma unroll
    for (int ks = 0; ks < KSTEPS; ++ks) {
        const int q = ks * 4 + kgrp;
        if (q < 21) {
            const int k   = (q * 11) >> 5;        // q/3
            const int ci0 = (q - 3 * k) * 8;
#pragma unroll
            for (int j = 0; j < 8; ++j)
                br[ks][j] = wbf[((ci0 + j) * COUT_ + c_out) * K_ + k];
        } else {
#pragma unroll
            for (int j = 0; j < 8; ++j) br[ks][j] = 0;  // zero-pad K
        }
    }
    __syncthreads();   // everyone done with wbf; xs may overwrite

    // ---- (4) convert + xs write (aliases wbf region)
#pragma unroll
    for (int it = 0; it < 5; ++it) {
        const int idx = tid + it * 384;
        if (idx < 1728) {
            const int p  = idx % 36;
            const int r  = idx / 36;
            const int cp = r % 12;
            const int hl = r / 12;
            ((unsigned*)xs)[(hl * 36 + p) * 12 + cp] = cvt_pk_bf16(v0r[it], v1r[it]);
        }
    }
    __syncthreads();

    // ---- (5) compute + epilogue (R10 exactly)
    int koff[KSTEPS];
#pragma unroll
    for (int ks = 0; ks < KSTEPS; ++ks) {
        const int q   = ks * 4 + kgrp;
        const int k   = (q * 11) >> 5;
        const int ci0 = (q - 3 * k) * 8;
        koff[ks] = k * 24 + ci0;
    }

    float* cbase = out + ((size_t)(b * 192 + g * COUT_ + c_out)) * HW_;

#pragma unroll
    for (int mt = 0; mt < MT_; ++mt) {
        const int mA = mt * 16 + cgrp;
        const int hA = mA / 28;
        const int tA = mA - hA * 28;
        const int abase = (hA * 36 + tA) * 24;
        float4v acc = (float4v)(0.0f);
#pragma unroll
        for (int ks = 0; ks < KSTEPS; ++ks) {
            const short8 a = *(const short8*)&xs[abase + koff[ks]];
            acc = __builtin_amdgcn_mfma_f32_16x16x32_bf16(a, br[ks], acc, 0, 0, 0);
        }
        // D-quad j=0..3 = 4 consecutive t in one h-row (m0 % 4 == 0, 4 | 28)
        const int m0 = mt * 16 + kgrp * 4;
        const int hl = m0 / 28;
        const int t0 = m0 - hl * 28;
        const int hd = 4 * ht + hl;       // output row (roll absorbed in rsrc)
        float4 v; v.x = acc[0]; v.y = acc[1]; v.z = acc[2]; v.w = acc[3];
        *(float4*)&cbase[hd * W_ + t0] = v;
    }
}

extern "C" void kernel_launch(void* const* d_in, const int* in_sizes, int n_in,
                              void* d_out, int out_size, void* d_ws, size_t ws_size,
                              hipStream_t stream) {
    const float* x = (const float*)d_in[0];
    const float* w = (const float*)d_in[1];
    float* out = (float*)d_out;
    conv_mfma_kernel<<<B_ * 2 * 7, 384, 0, stream>>>(x, w, out);
}

// Round 17
// 27.710 us; speedup vs baseline: 1.4593x; 1.4593x over previous
//
#include <hip/hip_runtime.h>

// Grouped conv1d over W + roll(+1) along H, bf16 MFMA. Persistent, 2 blk/CU.
// x: (128, 48, 28, 28) f32, channel = g*24+ci
// w: (24, 96, 7) f32, w[ci][o][k], shared across the 2 groups
// out: (128, 192, 28, 28) f32, channel = g*96+o
//
// FINAL (= R9, measured best 27.9us): single dispatch; block (b,g,s) takes
// interleaved tiles {s, s+2, ...}; 2 blocks/CU overlap each other's
// stage/barrier phases. In-block w->bf16 LDS bounce (32.2KB, aliased by xs
// dbuf after extraction), B operand in 24 VGPR, k-permuted ds_read_b128 A
// path, aligned float4 quad epilogue (measured ideal WRITE 75.3MB).
//
// Session elimination matrix (9 falsified theories, 6 structures, all
// 27.9-30.3us): staging VALU (R13), LDS traffic/conflicts (R11/R12), MFMA
// chains (R12), B-frag sourcing (R5/R6/R16), store vectorization (R6),
// DRAM burst order (R14), blocks/CU & dispatch count (R7/R9/R10),
// intra-block pipelining (R15). Floor = 94.6MB @ 6.3TB/s = 15us + ~5-10us
// dispatch/graph overhead; ~28us is the practical plateau here.
//
// GEMM per tile: M=112 (4 output rows x 28 W), N=96, K=168 pad 192.
// k-permutation (A and B must match): q = ks*4+kgrp (0..23);
//   q<21: k=q/3, ci=(q%3)*8+j ; q>=21: zero (B side).
// Block owns OUTPUT rows 4ht..4ht+3; src rows (4ht+hl-1) mod 28 absorb roll.

typedef __attribute__((ext_vector_type(8))) short short8;
typedef __attribute__((ext_vector_type(4))) float float4v;

#define B_     128
#define H_     28
#define W_     28
#define CIN_   24
#define COUT_  96
#define K_     7
#define KSTEPS 6
#define NT_    6
#define MT_    7
#define HW_    784

// float -> bf16 bits, RNE
static __device__ __forceinline__ unsigned f2bf_u(float f) {
    union { float f; unsigned u; } v; v.f = f;
    return (v.u + 0x7fffu + ((v.u >> 16) & 1u)) >> 16;
}

__global__ __launch_bounds__(384, 2)
void conv_mfma_kernel(const float* __restrict__ x,
                      const float* __restrict__ w,
                      float* __restrict__ out) {
    const int bid  = blockIdx.x;          // 512 = b*4 + g*2 + s
    const int s    = bid & 1;
    const int g    = (bid >> 1) & 1;
    const int b    = bid >> 2;
    const int ntile = 4 - s;              // s=0: tiles 0,2,4,6 ; s=1: 1,3,5
    const int tid  = threadIdx.x;
    const int lane = tid & 63;
    const int nt   = tid >> 6;            // wave = N-tile, 0..5
    const int cgrp = lane & 15;
    const int kgrp = lane >> 4;

    // LDS union: prologue wbf[24][96][7] bf16 (32256B); then xs dbuf 2x6912B.
    __shared__ __align__(16) char smem[32256];
    short* wbf = (short*)smem;
    short* xs0 = (short*)smem;            // [4][36][24] bf16
    short* xs1 = (short*)(smem + 6912);

    // ---- wbf: coalesced w read (16128 floats = 4032 float4), bf16 convert
    for (int i = tid; i < 4032; i += 384) {
        const float4 v = ((const float4*)w)[i];
        const unsigned lo = f2bf_u(v.x) | (f2bf_u(v.y) << 16);
        const unsigned hi = f2bf_u(v.z) | (f2bf_u(v.w) << 16);
        ((uint2*)wbf)[i] = make_uint2(lo, hi);
    }
    __syncthreads();

    // ---- B fragments -> 24 VGPR (48 ds_read_u16/lane, once per block)
    const int c_out = nt * 16 + cgrp;     // 0..95 within group
    short8 br[KSTEPS];
#pragma unroll
    for (int ks = 0; ks < KSTEPS; ++ks) {
        const int q = ks * 4 + kgrp;
        if (q < 21) {
            const int k   = (q * 11) >> 5;        // q/3
            const int ci0 = (q - 3 * k) * 8;
#pragma unroll
            for (int j = 0; j < 8; ++j)
                br[ks][j] = wbf[((ci0 + j) * COUT_ + c_out) * K_ + k];
        } else {
#pragma unroll
            for (int j = 0; j < 8; ++j) br[ks][j] = 0;  // zero-pad K
        }
    }
    __syncthreads();   // done reading wbf; xs buffers may overwrite it

    // Per-lane k-step LDS offsets (A side of the shared k permutation)
    int koff[KSTEPS];
#pragma unroll
    for (int ks = 0; ks < KSTEPS; ++ks) {
        const int q   = ks * 4 + kgrp;
        const int k   = (q * 11) >> 5;
        const int ci0 = (q - 3 * k) * 8;
        koff[ks] = k * 24 + ci0;
    }

    float* cbase = out + ((size_t)(b * 192 + g * COUT_ + c_out)) * HW_;

    // ---- staging helpers: 1728 packed dwords per tile, 5 iters/thread
    float v0r[5], v1r[5];
    auto stage_load = [&](int ht) {
#pragma unroll
        for (int it = 0; it < 5; ++it) {
            const int idx = tid + it * 384;
            if (idx < 1728) {
                const int p  = idx % 36;
                const int r  = idx / 36;
                const int cp = r % 12;
                const int hl = r / 12;
                const int ws = p - 3;
                const int rsrc = (4 * ht + hl + 27) % 28;
                float a0 = 0.0f, a1 = 0.0f;
                if (ws >= 0 && ws < W_) {
                    const size_t base =
                        ((size_t)(b * 48 + g * CIN_ + cp * 2) * H_ + rsrc) * W_ + ws;
                    a0 = x[base];
                    a1 = x[base + (size_t)HW_];
                }
                v0r[it] = a0; v1r[it] = a1;
            }
        }
    };
    auto stage_write = [&](short* xs) {
#pragma unroll
        for (int it = 0; it < 5; ++it) {
            const int idx = tid + it * 384;
            if (idx < 1728) {
                const int p  = idx % 36;
                const int r  = idx / 36;
                const int cp = r % 12;
                const int hl = r / 12;
                ((unsigned*)xs)[(hl * 36 + p) * 12 + cp] =
                    f2bf_u(v0r[it]) | (f2bf_u(v1r[it]) << 16);
            }
        }
    };
    auto compute_tile = [&](const short* xs, int ht) {
#pragma unroll
        for (int mt = 0; mt < MT_; ++mt) {
            const int mA = mt * 16 + cgrp;
            const int hA = mA / 28;
            const int tA = mA - hA * 28;
            const int abase = (hA * 36 + tA) * 24;
            float4v acc = (float4v)(0.0f);
#pragma unroll
            for (int ks = 0; ks < KSTEPS; ++ks) {
                const short8 a = *(const short8*)&xs[abase + koff[ks]];
                acc = __builtin_amdgcn_mfma_f32_16x16x32_bf16(a, br[ks], acc, 0, 0, 0);
            }
            // D-quad j=0..3 = 4 consecutive t in one h-row (m0 % 4 == 0, 4|28)
            const int m0 = mt * 16 + kgrp * 4;
            const int hl = m0 / 28;
            const int t0 = m0 - hl * 28;
            const int hd = 4 * ht + hl;
            float4 v; v.x = acc[0]; v.y = acc[1]; v.z = acc[2]; v.w = acc[3];
            *(float4*)&cbase[hd * W_ + t0] = v;
        }
    };

    // ---- pipelined tile loop over this block's interleaved tiles
    stage_load(s);
    stage_write(xs0);
    __syncthreads();
    for (int tix = 0; tix < ntile; ++tix) {
        const int ht = s + 2 * tix;
        const short* cur = (tix & 1) ? xs1 : xs0;
        short*       nxt = (tix & 1) ? xs0 : xs1;
        if (tix < ntile - 1) stage_load(ht + 2);   // issue next tile's loads
        compute_tile(cur, ht);                     // hides load latency
        if (tix < ntile - 1) stage_write(nxt);     // vmcnt-wait, cvt, ds_write
        __syncthreads();
    }
}

extern "C" void kernel_launch(void* const* d_in, const int* in_sizes, int n_in,
                              void* d_out, int out_size, void* d_ws, size_t ws_size,
                              hipStream_t stream) {
    const float* x = (const float*)d_in[0];
    const float* w = (const float*)d_in[1];
    float* out = (float*)d_out;
    conv_mfma_kernel<<<B_ * 4, 384, 0, stream>>>(x, w, out);
}